// Round 1
// baseline (1257.062 us; speedup 1.0000x reference)
//
#include <hip/hip_runtime.h>

#define SEQ 768
#define PRED 192
#define ENC 321
#define NB 2
#define BE (NB*ENC)

__device__ __forceinline__ float4 ldg4(const float* p) {
    return *reinterpret_cast<const float4*>(p);
}

__device__ __forceinline__ int d_Lw(int s)    { return s==0?192:(s==1?384:768); }
__device__ __forceinline__ int d_Hoff(int s)  { return s==0?0:(s==1?49152:147456); }
__device__ __forceinline__ int d_twoff(int s) { return s==0?0:(s==1?6144:18432); }

// ------------------------------------------------------------------
// per-(b,j) mean / stdev over t
__global__ void k_stats(const float* __restrict__ hist,
                        float* __restrict__ meanb, float* __restrict__ stdb) {
    int j  = blockIdx.x*64 + threadIdx.x;
    int b  = blockIdx.y;
    int ty = threadIdx.y;
    float s = 0.f, s2 = 0.f;
    if (j < ENC) {
        for (int t = ty; t < SEQ; t += 4) {
            float v = hist[(size_t)b*SEQ*ENC + (size_t)t*ENC + j];
            s += v; s2 += v*v;
        }
    }
    __shared__ float l1[4][64], l2[4][64];
    l1[ty][threadIdx.x] = s; l2[ty][threadIdx.x] = s2;
    __syncthreads();
    if (ty == 0 && j < ENC) {
        float S  = l1[0][threadIdx.x]+l1[1][threadIdx.x]+l1[2][threadIdx.x]+l1[3][threadIdx.x];
        float S2 = l2[0][threadIdx.x]+l2[1][threadIdx.x]+l2[2][threadIdx.x]+l2[3][threadIdx.x];
        float m   = S * (1.f/SEQ);
        float var = S2 * (1.f/SEQ) - m*m;
        meanb[b*ENC+j] = m;
        stdb[b*ENC+j]  = sqrtf(var + 1e-5f);
    }
}

// normalized x (same (b,t,j) layout as history)
__global__ void k_norm(const float* __restrict__ hist,
                       const float* __restrict__ meanb, const float* __restrict__ stdb,
                       const float* __restrict__ aw, const float* __restrict__ ab,
                       float* __restrict__ xn) {
    int i = blockIdx.x*256 + threadIdx.x;
    if (i >= NB*SEQ*ENC) return;
    int j = i % ENC;
    int b = i / (SEQ*ENC);
    float v = (hist[i] - meanb[b*ENC+j]) / stdb[b*ENC+j];
    xn[i] = v * aw[j] + ab[j];
}

// twiddles: tw[s][k][m] = e^{-2pi i k m / Lw};  gt[s][k][r] = kappa_k * e^{-2pi i k r/Lw}
__global__ void k_tw(float2* __restrict__ tw, float2* __restrict__ gt) {
    int i = blockIdx.x*256 + threadIdx.x;
    if (i >= 43008) return;
    int s, rem;
    if (i < 6144)       { s=0; rem=i; }
    else if (i < 18432) { s=1; rem=i-6144; }
    else                { s=2; rem=i-18432; }
    int Lw = d_Lw(s);
    int k = rem / Lw, m = rem % Lw;
    const float TWO_PI = 6.28318530717958647692f;
    int km = (k*m) % Lw;
    float c, sn;
    sincosf(TWO_PI * km / Lw, &sn, &c);   // note: sincosf(x, &sin, &cos)
    tw[i] = make_float2(c, -sn);
    int e = (k*(PRED-1-m)) % Lw; if (e < 0) e += Lw;
    float c2, s2v;
    sincosf(TWO_PI * e / Lw, &s2v, &c2);
    float coef = (k==0 ? 1.f : 2.f) / (float)Lw;
    gt[i] = make_float2(coef*c2, coef*s2v);
}

// H[s][0] = B_s ; apow buf0 = A_s
__global__ void k_hinit(const float* __restrict__ Ast, const float* __restrict__ Bst,
                        float* __restrict__ apow, float* __restrict__ Hbuf) {
    int i = blockIdx.x*256 + threadIdx.x;
    if (i < 3*65536) apow[i] = Ast[i];
    if (i < 3*256) {
        int s = i >> 8, n = i & 255;
        Hbuf[d_Hoff(s) + n] = Bst[i];
    }
}

// ---------- generic 64x64 tile GEMMs ----------
// NT: C[m,n] = sum_q A[m,q]*B[n,q]
__device__ __forceinline__ void gemm_tile_nt(
    const float* __restrict__ A, int lda, int Arows,
    const float* __restrict__ B, int ldb, int Brows,
    float* __restrict__ C, int ldc, int m0, int n0, int K)
{
    __shared__ float Ls[64][17];
    __shared__ float Rs[64][17];
    int tid = threadIdx.x;
    int tm = tid >> 4, tn = tid & 15;
    float acc[4][4] = {};
    for (int kt = 0; kt < K; kt += 16) {
        __syncthreads();
        #pragma unroll
        for (int e = 0; e < 4; e++) {
            int idx = tid + e*256;
            int r = idx >> 4, q = idx & 15;
            int am = m0 + r;
            Ls[r][q] = (am < Arows) ? A[(size_t)am*lda + kt + q] : 0.f;
            int bn = n0 + r;
            Rs[r][q] = (bn < Brows) ? B[(size_t)bn*ldb + kt + q] : 0.f;
        }
        __syncthreads();
        #pragma unroll
        for (int q = 0; q < 16; q++) {
            float a[4], bb[4];
            #pragma unroll
            for (int i = 0; i < 4; i++) a[i]  = Ls[tm*4+i][q];
            #pragma unroll
            for (int j = 0; j < 4; j++) bb[j] = Rs[tn*4+j][q];
            #pragma unroll
            for (int i = 0; i < 4; i++)
                #pragma unroll
                for (int j = 0; j < 4; j++)
                    acc[i][j] = fmaf(a[i], bb[j], acc[i][j]);
        }
    }
    #pragma unroll
    for (int i = 0; i < 4; i++) {
        int m = m0 + tm*4 + i; if (m >= Arows) continue;
        #pragma unroll
        for (int j = 0; j < 4; j++) {
            int n = n0 + tn*4 + j; if (n >= Brows) continue;
            C[(size_t)m*ldc + n] = acc[i][j];
        }
    }
}

// NN: C[m,n] = sum_q A[m,q]*B[q,n]
__device__ __forceinline__ void gemm_tile_nn(
    const float* __restrict__ A, int lda, int Arows,
    const float* __restrict__ B, int ldb, int Bcols,
    float* __restrict__ C, int ldc, int m0, int n0, int K)
{
    __shared__ float Ls[64][17];
    __shared__ float Bs[16][65];
    int tid = threadIdx.x;
    int tm = tid >> 4, tn = tid & 15;
    float acc[4][4] = {};
    for (int kt = 0; kt < K; kt += 16) {
        __syncthreads();
        #pragma unroll
        for (int e = 0; e < 4; e++) {
            int idx = tid + e*256;
            int r = idx >> 4, q = idx & 15;
            int am = m0 + r;
            Ls[r][q] = (am < Arows) ? A[(size_t)am*lda + kt + q] : 0.f;
        }
        #pragma unroll
        for (int e = 0; e < 4; e++) {
            int idx = tid + e*256;
            int q = idx >> 6, c = idx & 63;
            int bn = n0 + c;
            Bs[q][c] = (bn < Bcols) ? B[(size_t)(kt+q)*ldb + bn] : 0.f;
        }
        __syncthreads();
        #pragma unroll
        for (int q = 0; q < 16; q++) {
            float a[4], bb[4];
            #pragma unroll
            for (int i = 0; i < 4; i++) a[i]  = Ls[tm*4+i][q];
            #pragma unroll
            for (int j = 0; j < 4; j++) bb[j] = Bs[q][tn*4+j];
            #pragma unroll
            for (int i = 0; i < 4; i++)
                #pragma unroll
                for (int j = 0; j < 4; j++)
                    acc[i][j] = fmaf(a[i], bb[j], acc[i][j]);
        }
    }
    #pragma unroll
    for (int i = 0; i < 4; i++) {
        int m = m0 + tm*4 + i; if (m >= Arows) continue;
        #pragma unroll
        for (int j = 0; j < 4; j++) {
            int n = n0 + tn*4 + j; if (n >= Bcols) continue;
            C[(size_t)m*ldc + n] = acc[i][j];
        }
    }
}

// one doubling level: fill H[mc..min(2mc,Lw)) = H[0..]*Apow^T ; square Apow
__global__ void __launch_bounds__(256) k_hlevel(float* __restrict__ Hbuf,
                                                float* __restrict__ apow,
                                                int par, int mc) {
    int s = blockIdx.z;
    int Lw = d_Lw(s);
    const float* Asrc = apow + (size_t)par*(3*65536) + (size_t)s*65536;
    float* Adst       = apow + (size_t)(1-par)*(3*65536) + (size_t)s*65536;
    float* H = Hbuf + d_Hoff(s);
    int yt = blockIdx.y, xt = blockIdx.x;
    if (yt < 4) {
        if (mc >= Lw) return;
        int rows = min(mc, Lw - mc);
        if (yt*64 >= rows) return;
        gemm_tile_nt(H, 256, rows, Asrc, 256, 256, H + (size_t)mc*256, 256,
                     yt*64, xt*64, 256);
    } else {
        if (2*mc >= Lw) return;
        gemm_tile_nn(Asrc, 256, 256, Asrc, 256, 256, Adst, 256,
                     (yt-4)*64, xt*64, 256);
    }
}

// build G' rows for k-chunk: G[r, (kk,n,{re,im})] = kappa_k w^r * P_k[Lw-1-r, n]
__global__ void k_gbuild(const float* __restrict__ Hbuf,
                         const float2* __restrict__ tw, const float2* __restrict__ gt,
                         float* __restrict__ Gst, int s, int k0, int KC) {
    int tid = blockIdx.x*256 + threadIdx.x;
    int kk = tid >> 8;
    int n  = tid & 255;
    int Lw = d_Lw(s);
    int k = k0 + kk;
    const float2* twk = tw + d_twoff(s) + (size_t)k*Lw;
    const float2* gtk = gt + d_twoff(s) + (size_t)k*Lw;
    const float* H = Hbuf + d_Hoff(s);
    float pr = 0.f, pi = 0.f;
    int KD2 = KC*256;  // row stride in float2
    float2* G2 = (float2*)Gst;
    for (int m = 0; m < Lw; m++) {
        float h = H[m*256 + n];
        float2 t = twk[m];
        pr = fmaf(t.x, h, pr);
        pi = fmaf(t.y, h, pi);
        int r = Lw-1-m;
        float2 g = gtk[r];
        G2[(size_t)r*KD2 + kk*256 + n] = make_float2(g.x*pr - g.y*pi, g.x*pi + g.y*pr);
    }
}

// pack B rows for k-chunk: Bp[(kk,n,0),o]=wr[n,o,k] ; Bp[(kk,n,1),o]=-wi[n,o,k]
__global__ void k_pack(const float* __restrict__ wr, const float* __restrict__ wi,
                       float* __restrict__ Bp, int s, int k0, int KC) {
    const float* WR = wr + (size_t)s*2097152;
    const float* WI = wi + (size_t)s*2097152;
    int n0 = blockIdx.x*4, o0 = blockIdx.y*32;
    __shared__ float sw[2][4][32][33];
    int tid = threadIdx.x;
    int total = 2*4*32*KC;
    for (int idx = tid; idx < total; idx += 256) {
        int kk = idx % KC;
        int o  = (idx/KC) & 31;
        int n  = (idx/(KC*32)) & 3;
        int wsel = idx/(KC*128);
        const float* W = wsel ? WI : WR;
        sw[wsel][n][o][kk] = W[(size_t)(n0+n)*8192 + (size_t)(o0+o)*32 + (k0+kk)];
    }
    __syncthreads();
    int totalo = KC*4*2*32;
    for (int idx = tid; idx < totalo; idx += 256) {
        int o    = idx & 31;
        int part = (idx>>5) & 1;
        int n    = (idx>>6) & 3;
        int kk   = idx>>8;
        float v = part ? -sw[1][n][o][kk] : sw[0][n][o][kk];
        int R = kk*512 + (n0+n)*2 + part;
        Bp[(size_t)R*256 + o0 + o] = v;
    }
}

// big GEMM: parts[z] (+)= G(Lw x Kd) * Bp(Kd x 256), 64x128 tiles, split-K
__global__ void __launch_bounds__(256) k_qgemm(
    const float* __restrict__ G, const float* __restrict__ Bp,
    float* __restrict__ parts, int Lw, int Kd, int Kblk, int accflag)
{
    int m0 = blockIdx.x*64, n0 = blockIdx.y*128;
    int z  = blockIdx.z;
    int kb = z*Kblk;
    __shared__ __align__(16) float AsT[16][68];
    __shared__ __align__(16) float BsT[16][132];
    int tid = threadIdx.x;
    int tm = tid >> 4, tn = tid & 15;
    float acc[4][8] = {};
    for (int kt = 0; kt < Kblk; kt += 16) {
        __syncthreads();
        {
            int m = tid >> 2, q4 = (tid & 3)*4;
            float4 f = ldg4(G + (size_t)(m0+m)*Kd + kb + kt + q4);
            AsT[q4+0][m] = f.x; AsT[q4+1][m] = f.y;
            AsT[q4+2][m] = f.z; AsT[q4+3][m] = f.w;
        }
        #pragma unroll
        for (int e = 0; e < 2; e++) {
            int idx = tid + e*256;
            int q = idx >> 5, c4 = (idx & 31)*4;
            float4 f = ldg4(Bp + (size_t)(kb+kt+q)*256 + n0 + c4);
            *reinterpret_cast<float4*>(&BsT[q][c4]) = f;
        }
        __syncthreads();
        #pragma unroll
        for (int q = 0; q < 16; q++) {
            float4 a  = *reinterpret_cast<float4*>(&AsT[q][tm*4]);
            float4 b0 = *reinterpret_cast<float4*>(&BsT[q][tn*4]);
            float4 b1 = *reinterpret_cast<float4*>(&BsT[q][64+tn*4]);
            float av[4] = {a.x,a.y,a.z,a.w};
            float bv[8] = {b0.x,b0.y,b0.z,b0.w,b1.x,b1.y,b1.z,b1.w};
            #pragma unroll
            for (int i = 0; i < 4; i++)
                #pragma unroll
                for (int j = 0; j < 8; j++)
                    acc[i][j] = fmaf(av[i], bv[j], acc[i][j]);
        }
    }
    #pragma unroll
    for (int i = 0; i < 4; i++) {
        int m = m0 + tm*4 + i;
        float* p0 = parts + ((size_t)z*Lw + m)*256 + n0 + tn*4;
        float* p1 = p0 + 64;
        if (accflag) {
            #pragma unroll
            for (int j = 0; j < 4; j++) { p0[j] += acc[i][j]; p1[j] += acc[i][4+j]; }
        } else {
            #pragma unroll
            for (int j = 0; j < 4; j++) { p0[j] = acc[i][j]; p1[j] = acc[i][4+j]; }
        }
    }
}

__global__ void k_reduce(const float* __restrict__ parts, float* __restrict__ Q,
                         int Lw, int SK) {
    int i = blockIdx.x*256 + threadIdx.x;
    int tot = Lw*256;
    if (i >= tot) return;
    float v = 0.f;
    for (int z = 0; z < SK; z++) v += parts[(size_t)z*tot + i];
    Q[i] = v;
}

// T[r,p] = sum_o Q[r,o] * Esub[p,o]
__global__ void __launch_bounds__(256) k_tgemm(const float* __restrict__ Q,
                                               const float* __restrict__ Esub,
                                               float* __restrict__ T, int Lw) {
    gemm_tile_nt(Q, 256, Lw, Esub, 256, 192, T, 192,
                 blockIdx.x*64, blockIdx.y*64, 256);
}

// Mtot[p,t] = sum_i mw[i] * T_i[t-off_i, p]
__global__ void k_mtot(const float* __restrict__ T, const float* __restrict__ mlpw,
                       float* __restrict__ M) {
    int i = blockIdx.x*256 + threadIdx.x;
    if (i >= 192*768) return;
    int p = i / 768, t = i % 768;
    float v = mlpw[2] * T[110592 + (size_t)t*192 + p];
    if (t >= 384) v += mlpw[1] * T[36864 + (size_t)(t-384)*192 + p];
    if (t >= 576) v += mlpw[0] * T[(size_t)(t-576)*192 + p];
    M[i] = v;
}

// out[b,p,j] = ((Mtot @ x)[p,(b,j)] + mb - ab[j])/(aw[j]+1e-10)*std + mean
__global__ void __launch_bounds__(256) k_final(
    const float* __restrict__ M, const float* __restrict__ xn,
    const float* __restrict__ aw, const float* __restrict__ ab,
    const float* __restrict__ meanb, const float* __restrict__ stdb,
    const float* __restrict__ mlpb, float* __restrict__ out)
{
    __shared__ float Ls[64][17];
    __shared__ float Bs[16][65];
    int p0 = blockIdx.x*64, c0 = blockIdx.y*64;
    int tid = threadIdx.x, tm = tid >> 4, tn = tid & 15;
    float acc[4][4] = {};
    for (int kt = 0; kt < 768; kt += 16) {
        __syncthreads();
        #pragma unroll
        for (int e = 0; e < 4; e++) {
            int idx = tid + e*256;
            int r = idx >> 4, q = idx & 15;
            Ls[r][q] = M[(size_t)(p0+r)*768 + kt + q];
        }
        #pragma unroll
        for (int e = 0; e < 4; e++) {
            int idx = tid + e*256;
            int q = idx >> 6, c = idx & 63;
            int cc = c0 + c;
            float v = 0.f;
            if (cc < BE) {
                int b = (cc >= ENC) ? 1 : 0;
                int j = cc - b*ENC;
                v = xn[(size_t)b*SEQ*ENC + (size_t)(kt+q)*ENC + j];
            }
            Bs[q][c] = v;
        }
        __syncthreads();
        #pragma unroll
        for (int q = 0; q < 16; q++) {
            float a[4], bb[4];
            #pragma unroll
            for (int i = 0; i < 4; i++) a[i]  = Ls[tm*4+i][q];
            #pragma unroll
            for (int j = 0; j < 4; j++) bb[j] = Bs[q][tn*4+j];
            #pragma unroll
            for (int i = 0; i < 4; i++)
                #pragma unroll
                for (int j = 0; j < 4; j++)
                    acc[i][j] = fmaf(a[i], bb[j], acc[i][j]);
        }
    }
    float mb = mlpb[0];
    #pragma unroll
    for (int i = 0; i < 4; i++) {
        int p = p0 + tm*4 + i;
        #pragma unroll
        for (int j = 0; j < 4; j++) {
            int cc = c0 + tn*4 + j;
            if (cc < BE) {
                int b = (cc >= ENC) ? 1 : 0;
                int jj = cc - b*ENC;
                float v = (acc[i][j] + mb - ab[jj]) / (aw[jj] + 1e-10f);
                v = v * stdb[b*ENC+jj] + meanb[b*ENC+jj];
                out[(size_t)b*(PRED*ENC) + (size_t)p*ENC + jj] = v;
            }
        }
    }
}

// ------------------------------------------------------------------
extern "C" void kernel_launch(void* const* d_in, const int* in_sizes, int n_in,
                              void* d_out, int out_size, void* d_ws, size_t ws_size,
                              hipStream_t stream)
{
    const float* hist = (const float*)d_in[0];
    const float* aw   = (const float*)d_in[2];
    const float* ab   = (const float*)d_in[3];
    const float* Ast  = (const float*)d_in[4];
    const float* Bst  = (const float*)d_in[5];
    const float* E[3] = {(const float*)d_in[6], (const float*)d_in[7], (const float*)d_in[8]};
    const float* wr   = (const float*)d_in[9];
    const float* wi   = (const float*)d_in[10];
    const float* mlpw = (const float*)d_in[11];
    const float* mlpb = (const float*)d_in[12];
    float* out = (float*)d_out;

    const size_t fixedf = 493056 + 642 + 642 + 344064 + 2*3*65536
                        + 86016 + 86016 + 196608 + 258048 + 147456;
    auto need = [&](int kc, int sk) -> size_t {
        return (fixedf + (size_t)768*kc*512 + (size_t)kc*512*256 + (size_t)sk*768*256) * 4;
    };
    int KC, SK;
    if (ws_size >= need(32,32))     { KC = 32; SK = 32; }
    else if (ws_size >= need(8,8))  { KC = 8;  SK = 8;  }
    else                            { KC = 2;  SK = 4;  }

    float* w = (float*)d_ws;
    float* xn    = w; w += 493056;
    float* meanb = w; w += 642;
    float* stdb  = w; w += 642;
    float* Hbuf  = w; w += 344064;
    float* apow  = w; w += 2*3*65536;
    float2* tw   = (float2*)w; w += 86016;
    float2* gt   = (float2*)w; w += 86016;
    float* Gst   = w; w += (size_t)768*KC*512;
    float* Bp    = w; w += (size_t)KC*512*256;
    float* parts = w; w += (size_t)SK*768*256;
    float* Qbuf  = w; w += 196608;
    float* Tbuf  = w; w += 258048;
    float* Mt    = w; w += 147456;

    k_stats<<<dim3(6,2), dim3(64,4), 0, stream>>>(hist, meanb, stdb);
    k_norm<<<1926, 256, 0, stream>>>(hist, meanb, stdb, aw, ab, xn);
    k_tw<<<168, 256, 0, stream>>>(tw, gt);
    k_hinit<<<768, 256, 0, stream>>>(Ast, Bst, apow, Hbuf);
    for (int lev = 0; lev < 10; lev++)
        k_hlevel<<<dim3(4,8,3), 256, 0, stream>>>(Hbuf, apow, lev & 1, 1 << lev);

    const int Lws[3]  = {192, 384, 768};
    const int Toff[3] = {0, 36864, 110592};
    int nch  = 32 / KC;
    int Kd   = KC * 512;
    int Kblk = Kd / SK;
    for (int s = 0; s < 3; s++) {
        int Lw = Lws[s];
        for (int c = 0; c < nch; c++) {
            k_gbuild<<<KC, 256, 0, stream>>>(Hbuf, tw, gt, Gst, s, c*KC, KC);
            k_pack<<<dim3(64,8), 256, 0, stream>>>(wr, wi, Bp, s, c*KC, KC);
            k_qgemm<<<dim3(Lw/64, 2, SK), 256, 0, stream>>>(Gst, Bp, parts, Lw, Kd, Kblk, c > 0);
        }
        k_reduce<<<(Lw*256 + 255)/256, 256, 0, stream>>>(parts, Qbuf, Lw, SK);
        k_tgemm<<<dim3(Lw/64, 3), 256, 0, stream>>>(Qbuf, E[s] + (size_t)(Lw-192)*256, Tbuf + Toff[s], Lw);
    }
    k_mtot<<<576, 256, 0, stream>>>(Tbuf, mlpw, Mt);
    k_final<<<dim3(3, 11), 256, 0, stream>>>(Mt, xn, aw, ab, meanb, stdb, mlpb, out);
}

// Round 2
// 603.924 us; speedup vs baseline: 2.0815x; 2.0815x over previous
//
#include <hip/hip_runtime.h>

#define SEQ 768
#define PRED 192
#define ENC 321
#define NB 2
#define BE (NB*ENC)
#define CH 96

__device__ __forceinline__ float4 ldg4(const float* p) {
    return *reinterpret_cast<const float4*>(p);
}

__device__ __forceinline__ int d_Lw(int s)    { return s==0?192:(s==1?384:768); }
__device__ __forceinline__ int d_Hoff(int s)  { return s==0?0:(s==1?49152:147456); }
__device__ __forceinline__ int d_twoff(int s) { return s==0?0:(s==1?6144:18432); }

// ------------------------------------------------------------------
__global__ void k_stats(const float* __restrict__ hist,
                        float* __restrict__ meanb, float* __restrict__ stdb) {
    int j  = blockIdx.x*64 + threadIdx.x;
    int b  = blockIdx.y;
    int ty = threadIdx.y;
    float s = 0.f, s2 = 0.f;
    if (j < ENC) {
        for (int t = ty; t < SEQ; t += 4) {
            float v = hist[(size_t)b*SEQ*ENC + (size_t)t*ENC + j];
            s += v; s2 += v*v;
        }
    }
    __shared__ float l1[4][64], l2[4][64];
    l1[ty][threadIdx.x] = s; l2[ty][threadIdx.x] = s2;
    __syncthreads();
    if (ty == 0 && j < ENC) {
        float S  = l1[0][threadIdx.x]+l1[1][threadIdx.x]+l1[2][threadIdx.x]+l1[3][threadIdx.x];
        float S2 = l2[0][threadIdx.x]+l2[1][threadIdx.x]+l2[2][threadIdx.x]+l2[3][threadIdx.x];
        float m   = S * (1.f/SEQ);
        float var = S2 * (1.f/SEQ) - m*m;
        meanb[b*ENC+j] = m;
        stdb[b*ENC+j]  = sqrtf(var + 1e-5f);
    }
}

__global__ void k_norm(const float* __restrict__ hist,
                       const float* __restrict__ meanb, const float* __restrict__ stdb,
                       const float* __restrict__ aw, const float* __restrict__ ab,
                       float* __restrict__ xn) {
    int i = blockIdx.x*256 + threadIdx.x;
    if (i >= NB*SEQ*ENC) return;
    int j = i % ENC;
    int b = i / (SEQ*ENC);
    float v = (hist[i] - meanb[b*ENC+j]) / stdb[b*ENC+j];
    xn[i] = v * aw[j] + ab[j];
}

__global__ void k_tw(float2* __restrict__ tw, float2* __restrict__ gt) {
    int i = blockIdx.x*256 + threadIdx.x;
    if (i >= 43008) return;
    int s, rem;
    if (i < 6144)       { s=0; rem=i; }
    else if (i < 18432) { s=1; rem=i-6144; }
    else                { s=2; rem=i-18432; }
    int Lw = d_Lw(s);
    int k = rem / Lw, m = rem % Lw;
    const float TWO_PI = 6.28318530717958647692f;
    int km = (k*m) % Lw;
    float c, sn;
    sincosf(TWO_PI * km / Lw, &sn, &c);
    tw[i] = make_float2(c, -sn);
    int e = (k*(PRED-1-m)) % Lw; if (e < 0) e += Lw;
    float c2, s2v;
    sincosf(TWO_PI * e / Lw, &s2v, &c2);
    float coef = (k==0 ? 1.f : 2.f) / (float)Lw;
    gt[i] = make_float2(coef*c2, coef*s2v);
}

__global__ void k_hinit(const float* __restrict__ Ast, const float* __restrict__ Bst,
                        float* __restrict__ apow, float* __restrict__ Hbuf) {
    int i = blockIdx.x*256 + threadIdx.x;
    if (i < 3*65536) apow[i] = Ast[i];
    if (i < 3*256) {
        int s = i >> 8, n = i & 255;
        Hbuf[d_Hoff(s) + n] = Bst[i];
    }
}

// ---------- 64x64 tile GEMM cores, float4 transposed-LDS fragments ----------
// NT: C[m,n] = sum_q A[m,q]*B[n,q]
__device__ __forceinline__ void gemm64nt(
    const float* __restrict__ A, int lda, int Arows,
    const float* __restrict__ B, int ldb,
    float* __restrict__ C, int ldc, int m0, int n0, int K)
{
    __shared__ __align__(16) float AsT[16][68];
    __shared__ __align__(16) float BsT[16][68];
    int tid = threadIdx.x;
    int tm = tid >> 4, tn = tid & 15;
    int lr = tid >> 2, lq = (tid & 3)*4;
    float acc[4][4] = {};
    for (int kt = 0; kt < K; kt += 16) {
        __syncthreads();
        int am = m0 + lr;
        float4 fa = (am < Arows) ? ldg4(A + (size_t)am*lda + kt + lq)
                                 : make_float4(0.f,0.f,0.f,0.f);
        float4 fb = ldg4(B + (size_t)(n0+lr)*ldb + kt + lq);
        AsT[lq+0][lr]=fa.x; AsT[lq+1][lr]=fa.y; AsT[lq+2][lr]=fa.z; AsT[lq+3][lr]=fa.w;
        BsT[lq+0][lr]=fb.x; BsT[lq+1][lr]=fb.y; BsT[lq+2][lr]=fb.z; BsT[lq+3][lr]=fb.w;
        __syncthreads();
        #pragma unroll
        for (int q = 0; q < 16; q++) {
            float4 a = *reinterpret_cast<float4*>(&AsT[q][tm*4]);
            float4 b = *reinterpret_cast<float4*>(&BsT[q][tn*4]);
            float av[4] = {a.x,a.y,a.z,a.w};
            float bv[4] = {b.x,b.y,b.z,b.w};
            #pragma unroll
            for (int i = 0; i < 4; i++)
                #pragma unroll
                for (int j = 0; j < 4; j++)
                    acc[i][j] = fmaf(av[i], bv[j], acc[i][j]);
        }
    }
    #pragma unroll
    for (int i = 0; i < 4; i++) {
        int m = m0 + tm*4 + i; if (m >= Arows) continue;
        #pragma unroll
        for (int j = 0; j < 4; j++)
            C[(size_t)m*ldc + n0 + tn*4 + j] = acc[i][j];
    }
}

// NN: C[m,n] = sum_q A[m,q]*B[q,n]
__device__ __forceinline__ void gemm64nn(
    const float* __restrict__ A, int lda,
    const float* __restrict__ B, int ldb,
    float* __restrict__ C, int ldc, int m0, int n0, int K)
{
    __shared__ __align__(16) float AsT[16][68];
    __shared__ __align__(16) float Bs[16][68];
    int tid = threadIdx.x;
    int tm = tid >> 4, tn = tid & 15;
    int lr = tid >> 2, lq = (tid & 3)*4;
    int blq = tid >> 4, blc = (tid & 15)*4;
    float acc[4][4] = {};
    for (int kt = 0; kt < K; kt += 16) {
        __syncthreads();
        float4 fa = ldg4(A + (size_t)(m0+lr)*lda + kt + lq);
        float4 fb = ldg4(B + (size_t)(kt+blq)*ldb + n0 + blc);
        AsT[lq+0][lr]=fa.x; AsT[lq+1][lr]=fa.y; AsT[lq+2][lr]=fa.z; AsT[lq+3][lr]=fa.w;
        *reinterpret_cast<float4*>(&Bs[blq][blc]) = fb;
        __syncthreads();
        #pragma unroll
        for (int q = 0; q < 16; q++) {
            float4 a = *reinterpret_cast<float4*>(&AsT[q][tm*4]);
            float4 b = *reinterpret_cast<float4*>(&Bs[q][tn*4]);
            float av[4] = {a.x,a.y,a.z,a.w};
            float bv[4] = {b.x,b.y,b.z,b.w};
            #pragma unroll
            for (int i = 0; i < 4; i++)
                #pragma unroll
                for (int j = 0; j < 4; j++)
                    acc[i][j] = fmaf(av[i], bv[j], acc[i][j]);
        }
    }
    #pragma unroll
    for (int i = 0; i < 4; i++) {
        int m = m0 + tm*4 + i;
        #pragma unroll
        for (int j = 0; j < 4; j++)
            C[(size_t)m*ldc + n0 + tn*4 + j] = acc[i][j];
    }
}

// one doubling level: fill H[mc..min(2mc,Lw)) = H[0..]*Apow^T ; square Apow
__global__ void __launch_bounds__(256) k_hlevel(float* __restrict__ Hbuf,
                                                float* __restrict__ apow,
                                                int par, int mc) {
    int s = blockIdx.z;
    int Lw = d_Lw(s);
    const float* Asrc = apow + (size_t)par*196608 + (size_t)s*65536;
    float* Adst       = apow + (size_t)(1-par)*196608 + (size_t)s*65536;
    float* H = Hbuf + d_Hoff(s);
    int yt = blockIdx.y, xt = blockIdx.x;
    if (yt < 4) {
        if (mc >= Lw) return;
        int rows = min(mc, Lw - mc);
        if (yt*64 >= rows) return;
        gemm64nt(H, 256, rows, Asrc, 256, H + (size_t)mc*256, 256,
                 yt*64, xt*64, 256);
    } else {
        if (2*mc >= Lw) return;
        gemm64nn(Asrc, 256, Asrc, 256, Adst, 256, (yt-4)*64, xt*64, 256);
    }
}

// ---------- blocked prefix scan for G ----------
// pass 1: per-chunk complex partial sums
__global__ void k_gscan1(const float* __restrict__ Hbuf, const float2* __restrict__ tw,
                         float2* __restrict__ psum) {
    int cg = blockIdx.x, k = blockIdx.y, n = threadIdx.x;
    int s, cl;
    if (cg < 2)      { s=0; cl=cg; }
    else if (cg < 6) { s=1; cl=cg-2; }
    else             { s=2; cl=cg-6; }
    int Lw = d_Lw(s);
    const float2* twk = tw + d_twoff(s) + (size_t)k*Lw;
    const float* H = Hbuf + d_Hoff(s);
    float pr = 0.f, pi = 0.f;
    int mbase = cl*CH;
    for (int mm = 0; mm < CH; mm++) {
        float h = H[(size_t)(mbase+mm)*256 + n];
        float2 t = twk[mbase+mm];
        pr = fmaf(t.x, h, pr);
        pi = fmaf(t.y, h, pi);
    }
    psum[((size_t)cg*32 + k)*256 + n] = make_float2(pr, pi);
}

// pass 2: add chunk-prefix offset, rescan chunk, write G rows
__global__ void k_gscan2(const float* __restrict__ Hbuf, const float2* __restrict__ tw,
                         const float2* __restrict__ gt, const float2* __restrict__ psum,
                         float2* __restrict__ G2, int s, int cbase) {
    int cl = blockIdx.x, k = blockIdx.y, n = threadIdx.x;
    int Lw = d_Lw(s);
    const float2* twk = tw + d_twoff(s) + (size_t)k*Lw;
    const float2* gtk = gt + d_twoff(s) + (size_t)k*Lw;
    const float* H = Hbuf + d_Hoff(s);
    float pr = 0.f, pi = 0.f;
    for (int c = 0; c < cl; c++) {
        float2 p = psum[((size_t)(cbase+c)*32 + k)*256 + n];
        pr += p.x; pi += p.y;
    }
    int mbase = cl*CH;
    for (int mm = 0; mm < CH; mm++) {
        int m = mbase + mm;
        float h = H[(size_t)m*256 + n];
        float2 t = twk[m];
        pr = fmaf(t.x, h, pr);
        pi = fmaf(t.y, h, pi);
        int r = Lw-1-m;
        float2 g = gtk[r];
        G2[(size_t)r*8192 + k*256 + n] = make_float2(g.x*pr - g.y*pi, g.x*pi + g.y*pr);
    }
}

// pack B rows: Bp[(kk,n,0),o]=wr[n,o,k] ; Bp[(kk,n,1),o]=-wi[n,o,k]
__global__ void k_pack(const float* __restrict__ wr, const float* __restrict__ wi,
                       float* __restrict__ Bp, int s) {
    const float* WR = wr + (size_t)s*2097152;
    const float* WI = wi + (size_t)s*2097152;
    int n0 = blockIdx.x*4, o0 = blockIdx.y*32;
    __shared__ float sw[2][4][32][33];
    int tid = threadIdx.x;
    for (int idx = tid; idx < 8192; idx += 256) {
        int kk = idx & 31;
        int o  = (idx>>5) & 31;
        int n  = (idx>>10) & 3;
        int wsel = idx>>12;
        const float* W = wsel ? WI : WR;
        sw[wsel][n][o][kk] = W[(size_t)(n0+n)*8192 + (size_t)(o0+o)*32 + kk];
    }
    __syncthreads();
    for (int idx = tid; idx < 8192; idx += 256) {
        int o    = idx & 31;
        int part = (idx>>5) & 1;
        int n    = (idx>>6) & 3;
        int kk   = idx>>8;
        float v = part ? -sw[1][n][o][kk] : sw[0][n][o][kk];
        int R = kk*512 + (n0+n)*2 + part;
        Bp[(size_t)R*256 + o0 + o] = v;
    }
}

// big GEMM: parts[z] = G(Lw x 16384) tile * Bp(16384 x 256), 64x64 tiles, split-K
__global__ void __launch_bounds__(256) k_qgemm(
    const float* __restrict__ G, const float* __restrict__ Bp,
    float* __restrict__ parts, int Lw, int Kblk)
{
    const int Kd = 16384;
    int m0 = blockIdx.x*64, n0 = blockIdx.y*64;
    int kb = blockIdx.z*Kblk;
    __shared__ __align__(16) float AsT[16][68];
    __shared__ __align__(16) float Bs[16][68];
    int tid = threadIdx.x;
    int tm = tid >> 4, tn = tid & 15;
    int alr = tid >> 2, alq = (tid & 3)*4;
    int blq = tid >> 4, blc = (tid & 15)*4;
    const float* Ap = G  + (size_t)(m0+alr)*Kd + kb + alq;
    const float* Bq = Bp + (size_t)(kb+blq)*256 + n0 + blc;
    float4 fa = ldg4(Ap);
    float4 fb = ldg4(Bq);
    float acc[4][4] = {};
    for (int kt = 0; kt < Kblk; kt += 16) {
        __syncthreads();
        AsT[alq+0][alr]=fa.x; AsT[alq+1][alr]=fa.y; AsT[alq+2][alr]=fa.z; AsT[alq+3][alr]=fa.w;
        *reinterpret_cast<float4*>(&Bs[blq][blc]) = fb;
        __syncthreads();
        if (kt + 16 < Kblk) {
            fa = ldg4(Ap + kt + 16);
            fb = ldg4(Bq + (size_t)(kt+16)*256);
        }
        #pragma unroll
        for (int q = 0; q < 16; q++) {
            float4 a = *reinterpret_cast<float4*>(&AsT[q][tm*4]);
            float4 b = *reinterpret_cast<float4*>(&Bs[q][tn*4]);
            float av[4] = {a.x,a.y,a.z,a.w};
            float bv[4] = {b.x,b.y,b.z,b.w};
            #pragma unroll
            for (int i = 0; i < 4; i++)
                #pragma unroll
                for (int j = 0; j < 4; j++)
                    acc[i][j] = fmaf(av[i], bv[j], acc[i][j]);
        }
    }
    #pragma unroll
    for (int i = 0; i < 4; i++) {
        int m = m0 + tm*4 + i;
        float4 o4 = make_float4(acc[i][0], acc[i][1], acc[i][2], acc[i][3]);
        *reinterpret_cast<float4*>(parts + ((size_t)blockIdx.z*Lw + m)*256 + n0 + tn*4) = o4;
    }
}

__global__ void k_reduce(const float* __restrict__ parts, float* __restrict__ Q,
                         int Lw, int SK) {
    int i = blockIdx.x*256 + threadIdx.x;
    int tot = Lw*256;
    if (i >= tot) return;
    float v = 0.f;
    for (int z = 0; z < SK; z++) v += parts[(size_t)z*tot + i];
    Q[i] = v;
}

// T[r,p] = sum_o Q[r,o] * Esub[p,o]   (batched over all scales)
__global__ void __launch_bounds__(256) k_tgemm(const float* __restrict__ Qall,
                                               const float* __restrict__ E0,
                                               const float* __restrict__ E1,
                                               const float* __restrict__ E2,
                                               float* __restrict__ T) {
    int mtg = blockIdx.x;
    int s, lm, Lw, rowoff, Toff;
    if (mtg < 3)      { s=0; lm=mtg;   Lw=192; rowoff=0;   Toff=0; }
    else if (mtg < 9) { s=1; lm=mtg-3; Lw=384; rowoff=192; Toff=36864; }
    else              { s=2; lm=mtg-9; Lw=768; rowoff=576; Toff=110592; }
    const float* Es = (s==0) ? E0 : ((s==1) ? E1 : E2);
    gemm64nt(Qall + (size_t)rowoff*256, 256, Lw,
             Es + (size_t)(Lw-192)*256, 256,
             T + Toff, 192, lm*64, blockIdx.y*64, 256);
}

// Mtot[p,t] = sum_i mw[i] * T_i[t-off_i, p]
__global__ void k_mtot(const float* __restrict__ T, const float* __restrict__ mlpw,
                       float* __restrict__ M) {
    int i = blockIdx.x*256 + threadIdx.x;
    if (i >= 192*768) return;
    int p = i / 768, t = i % 768;
    float v = mlpw[2] * T[110592 + (size_t)t*192 + p];
    if (t >= 384) v += mlpw[1] * T[36864 + (size_t)(t-384)*192 + p];
    if (t >= 576) v += mlpw[0] * T[(size_t)(t-576)*192 + p];
    M[i] = v;
}

// out[b,p,j] = ((Mtot @ x)[p,(b,j)] + mb - ab[j])/(aw[j]+1e-10)*std + mean
__global__ void __launch_bounds__(256) k_final(
    const float* __restrict__ M, const float* __restrict__ xn,
    const float* __restrict__ aw, const float* __restrict__ ab,
    const float* __restrict__ meanb, const float* __restrict__ stdb,
    const float* __restrict__ mlpb, float* __restrict__ out)
{
    __shared__ float Ls[64][17];
    __shared__ float Bs[16][65];
    int p0 = blockIdx.x*64, c0 = blockIdx.y*64;
    int tid = threadIdx.x, tm = tid >> 4, tn = tid & 15;
    float acc[4][4] = {};
    for (int kt = 0; kt < 768; kt += 16) {
        __syncthreads();
        #pragma unroll
        for (int e = 0; e < 4; e++) {
            int idx = tid + e*256;
            int r = idx >> 4, q = idx & 15;
            Ls[r][q] = M[(size_t)(p0+r)*768 + kt + q];
        }
        #pragma unroll
        for (int e = 0; e < 4; e++) {
            int idx = tid + e*256;
            int q = idx >> 6, c = idx & 63;
            int cc = c0 + c;
            float v = 0.f;
            if (cc < BE) {
                int b = (cc >= ENC) ? 1 : 0;
                int j = cc - b*ENC;
                v = xn[(size_t)b*SEQ*ENC + (size_t)(kt+q)*ENC + j];
            }
            Bs[q][c] = v;
        }
        __syncthreads();
        #pragma unroll
        for (int q = 0; q < 16; q++) {
            float a[4], bb[4];
            #pragma unroll
            for (int i = 0; i < 4; i++) a[i]  = Ls[tm*4+i][q];
            #pragma unroll
            for (int j = 0; j < 4; j++) bb[j] = Bs[q][tn*4+j];
            #pragma unroll
            for (int i = 0; i < 4; i++)
                #pragma unroll
                for (int j = 0; j < 4; j++)
                    acc[i][j] = fmaf(a[i], bb[j], acc[i][j]);
        }
    }
    float mb = mlpb[0];
    #pragma unroll
    for (int i = 0; i < 4; i++) {
        int p = p0 + tm*4 + i;
        #pragma unroll
        for (int j = 0; j < 4; j++) {
            int cc = c0 + tn*4 + j;
            if (cc < BE) {
                int b = (cc >= ENC) ? 1 : 0;
                int jj = cc - b*ENC;
                float v = (acc[i][j] + mb - ab[jj]) / (aw[jj] + 1e-10f);
                v = v * stdb[b*ENC+jj] + meanb[b*ENC+jj];
                out[(size_t)b*(PRED*ENC) + (size_t)p*ENC + jj] = v;
            }
        }
    }
}

// ------------------------------------------------------------------
extern "C" void kernel_launch(void* const* d_in, const int* in_sizes, int n_in,
                              void* d_out, int out_size, void* d_ws, size_t ws_size,
                              hipStream_t stream)
{
    const float* hist = (const float*)d_in[0];
    const float* aw   = (const float*)d_in[2];
    const float* ab   = (const float*)d_in[3];
    const float* Ast  = (const float*)d_in[4];
    const float* Bst  = (const float*)d_in[5];
    const float* E0   = (const float*)d_in[6];
    const float* E1   = (const float*)d_in[7];
    const float* E2   = (const float*)d_in[8];
    const float* wr   = (const float*)d_in[9];
    const float* wi   = (const float*)d_in[10];
    const float* mlpw = (const float*)d_in[11];
    const float* mlpb = (const float*)d_in[12];
    float* out = (float*)d_out;

    float* w = (float*)d_ws;
    float* xn    = w; w += 493056;
    float* meanb = w; w += 642;
    float* stdb  = w; w += 642;
    float* Hbuf  = w; w += 344064;
    float* apow  = w; w += 2*3*65536;
    float2* tw   = (float2*)w; w += 86016;
    float2* gt   = (float2*)w; w += 86016;
    float2* psum = (float2*)w; w += 229376;
    float* Gst   = w; w += 12582912;          // 768 x 16384 (max scale)
    float* Bp    = w; w += 4194304;           // 16384 x 256 (per scale)
    float* parts = w; w += 3145728;           // SK x Lw x 256 (= 3.1M all scales)
    float* Qall  = w; w += 344064;            // 1344 x 256
    float* Tbuf  = w; w += 258048;
    float* Mt    = w; w += 147456;
    // total 22,305,540 floats = 89.2 MB (< 100.3 MB proven available)

    k_stats<<<dim3(6,2), dim3(64,4), 0, stream>>>(hist, meanb, stdb);
    k_norm<<<1926, 256, 0, stream>>>(hist, meanb, stdb, aw, ab, xn);
    k_tw<<<168, 256, 0, stream>>>(tw, gt);
    k_hinit<<<768, 256, 0, stream>>>(Ast, Bst, apow, Hbuf);
    for (int lev = 0; lev < 10; lev++)
        k_hlevel<<<dim3(4,8,3), 256, 0, stream>>>(Hbuf, apow, lev & 1, 1 << lev);

    k_gscan1<<<dim3(14,32), 256, 0, stream>>>(Hbuf, tw, psum);

    const int Lws[3]   = {192, 384, 768};
    const int SKs[3]   = {64, 32, 16};
    const int Kblks[3] = {256, 512, 1024};
    const int cbase[3] = {0, 2, 6};
    const int rowoff[3]= {0, 192, 576};
    for (int s = 0; s < 3; s++) {
        int Lw = Lws[s];
        k_gscan2<<<dim3(Lw/CH, 32), 256, 0, stream>>>(Hbuf, tw, gt, psum, (float2*)Gst, s, cbase[s]);
        k_pack<<<dim3(64,8), 256, 0, stream>>>(wr, wi, Bp, s);
        k_qgemm<<<dim3(Lw/64, 4, SKs[s]), 256, 0, stream>>>(Gst, Bp, parts, Lw, Kblks[s]);
        k_reduce<<<Lw, 256, 0, stream>>>(parts, Qall + (size_t)rowoff[s]*256, Lw, SKs[s]);
    }
    k_tgemm<<<dim3(21,3), 256, 0, stream>>>(Qall, E0, E1, E2, Tbuf);
    k_mtot<<<576, 256, 0, stream>>>(Tbuf, mlpw, Mt);
    k_final<<<dim3(3, 11), 256, 0, stream>>>(Mt, xn, aw, ab, meanb, stdb, mlpb, out);
}

// Round 3
// 601.784 us; speedup vs baseline: 2.0889x; 1.0036x over previous
//
#include <hip/hip_runtime.h>

#define SEQ 768
#define PRED 192
#define ENC 321
#define NB 2
#define BE (NB*ENC)
#define CH 96

typedef float vf2 __attribute__((ext_vector_type(2)));

__device__ __forceinline__ float4 ldg4(const float* p) {
    return *reinterpret_cast<const float4*>(p);
}
__device__ __forceinline__ vf2 fma2(vf2 a, vf2 b, vf2 c) {
    return __builtin_elementwise_fma(a, b, c);
}

__device__ __forceinline__ int d_Lw(int s)    { return s==0?192:(s==1?384:768); }
__device__ __forceinline__ int d_Hoff(int s)  { return s==0?0:(s==1?49152:147456); }
__device__ __forceinline__ int d_twoff(int s) { return s==0?0:(s==1?6144:18432); }

// ------------------------------------------------------------------
__global__ void k_stats(const float* __restrict__ hist,
                        float* __restrict__ meanb, float* __restrict__ stdb) {
    int j  = blockIdx.x*64 + threadIdx.x;
    int b  = blockIdx.y;
    int ty = threadIdx.y;
    float s = 0.f, s2 = 0.f;
    if (j < ENC) {
        for (int t = ty; t < SEQ; t += 4) {
            float v = hist[(size_t)b*SEQ*ENC + (size_t)t*ENC + j];
            s += v; s2 += v*v;
        }
    }
    __shared__ float l1[4][64], l2[4][64];
    l1[ty][threadIdx.x] = s; l2[ty][threadIdx.x] = s2;
    __syncthreads();
    if (ty == 0 && j < ENC) {
        float S  = l1[0][threadIdx.x]+l1[1][threadIdx.x]+l1[2][threadIdx.x]+l1[3][threadIdx.x];
        float S2 = l2[0][threadIdx.x]+l2[1][threadIdx.x]+l2[2][threadIdx.x]+l2[3][threadIdx.x];
        float m   = S * (1.f/SEQ);
        float var = S2 * (1.f/SEQ) - m*m;
        meanb[b*ENC+j] = m;
        stdb[b*ENC+j]  = sqrtf(var + 1e-5f);
    }
}

__global__ void k_norm(const float* __restrict__ hist,
                       const float* __restrict__ meanb, const float* __restrict__ stdb,
                       const float* __restrict__ aw, const float* __restrict__ ab,
                       float* __restrict__ xn) {
    int i = blockIdx.x*256 + threadIdx.x;
    if (i >= NB*SEQ*ENC) return;
    int j = i % ENC;
    int b = i / (SEQ*ENC);
    float v = (hist[i] - meanb[b*ENC+j]) / stdb[b*ENC+j];
    xn[i] = v * aw[j] + ab[j];
}

__global__ void k_tw(float2* __restrict__ tw, float2* __restrict__ gt) {
    int i = blockIdx.x*256 + threadIdx.x;
    if (i >= 43008) return;
    int s, rem;
    if (i < 6144)       { s=0; rem=i; }
    else if (i < 18432) { s=1; rem=i-6144; }
    else                { s=2; rem=i-18432; }
    int Lw = d_Lw(s);
    int k = rem / Lw, m = rem % Lw;
    const float TWO_PI = 6.28318530717958647692f;
    int km = (k*m) % Lw;
    float c, sn;
    sincosf(TWO_PI * km / Lw, &sn, &c);
    tw[i] = make_float2(c, -sn);
    int e = (k*(PRED-1-m)) % Lw; if (e < 0) e += Lw;
    float c2, s2v;
    sincosf(TWO_PI * e / Lw, &s2v, &c2);
    float coef = (k==0 ? 1.f : 2.f) / (float)Lw;
    gt[i] = make_float2(coef*c2, coef*s2v);
}

__global__ void k_hinit(const float* __restrict__ Ast, const float* __restrict__ Bst,
                        float* __restrict__ apow, float* __restrict__ Hbuf) {
    int i = blockIdx.x*256 + threadIdx.x;
    if (i < 3*65536) apow[i] = Ast[i];
    if (i < 3*256) {
        int s = i >> 8, n = i & 255;
        Hbuf[d_Hoff(s) + n] = Bst[i];
    }
}

// ---------- 64x64 tile GEMM cores (pk-fma + register prefetch) ----------
// NT: C[m,n] = sum_q A[m,q]*B[n,q]
__device__ __forceinline__ void gemm64nt(
    const float* __restrict__ A, int lda, int Arows,
    const float* __restrict__ B, int ldb,
    float* __restrict__ C, int ldc, int m0, int n0, int K)
{
    __shared__ __align__(16) float AsT[16][68];
    __shared__ __align__(16) float BsT[16][68];
    int tid = threadIdx.x;
    int tm = tid >> 4, tn = tid & 15;
    int lr = tid >> 2, lq = (tid & 3)*4;
    bool aok = (m0 + lr) < Arows;
    const float* Ap = A + (size_t)(m0+lr)*lda + lq;
    const float* Bp = B + (size_t)(n0+lr)*ldb + lq;
    float4 fa = aok ? ldg4(Ap) : make_float4(0.f,0.f,0.f,0.f);
    float4 fb = ldg4(Bp);
    vf2 acc[2][4] = {};
    for (int kt = 0; kt < K; kt += 16) {
        __syncthreads();
        AsT[lq+0][lr]=fa.x; AsT[lq+1][lr]=fa.y; AsT[lq+2][lr]=fa.z; AsT[lq+3][lr]=fa.w;
        BsT[lq+0][lr]=fb.x; BsT[lq+1][lr]=fb.y; BsT[lq+2][lr]=fb.z; BsT[lq+3][lr]=fb.w;
        __syncthreads();
        if (kt + 16 < K) {
            fa = aok ? ldg4(Ap + kt + 16) : make_float4(0.f,0.f,0.f,0.f);
            fb = ldg4(Bp + kt + 16);
        }
        #pragma unroll
        for (int q = 0; q < 16; q++) {
            float4 a = *reinterpret_cast<float4*>(&AsT[q][tm*4]);
            float4 b = *reinterpret_cast<float4*>(&BsT[q][tn*4]);
            vf2 a01 = {a.x, a.y}, a23 = {a.z, a.w};
            vf2 b0 = {b.x,b.x}, b1 = {b.y,b.y}, b2 = {b.z,b.z}, b3 = {b.w,b.w};
            acc[0][0] = fma2(a01, b0, acc[0][0]);
            acc[0][1] = fma2(a01, b1, acc[0][1]);
            acc[0][2] = fma2(a01, b2, acc[0][2]);
            acc[0][3] = fma2(a01, b3, acc[0][3]);
            acc[1][0] = fma2(a23, b0, acc[1][0]);
            acc[1][1] = fma2(a23, b1, acc[1][1]);
            acc[1][2] = fma2(a23, b2, acc[1][2]);
            acc[1][3] = fma2(a23, b3, acc[1][3]);
        }
    }
    #pragma unroll
    for (int h = 0; h < 2; h++) {
        int m = m0 + tm*4 + h*2;
        #pragma unroll
        for (int j = 0; j < 4; j++) {
            if (m < Arows)     C[(size_t)m*ldc + n0 + tn*4 + j]     = acc[h][j].x;
            if (m + 1 < Arows) C[(size_t)(m+1)*ldc + n0 + tn*4 + j] = acc[h][j].y;
        }
    }
}

// NN: C[m,n] = sum_q A[m,q]*B[q,n]
__device__ __forceinline__ void gemm64nn(
    const float* __restrict__ A, int lda,
    const float* __restrict__ B, int ldb,
    float* __restrict__ C, int ldc, int m0, int n0, int K)
{
    __shared__ __align__(16) float AsT[16][68];
    __shared__ __align__(16) float Bs[16][68];
    int tid = threadIdx.x;
    int tm = tid >> 4, tn = tid & 15;
    int lr = tid >> 2, lq = (tid & 3)*4;
    int blq = tid >> 4, blc = (tid & 15)*4;
    const float* Ap = A + (size_t)(m0+lr)*lda + lq;
    const float* Bp = B + (size_t)blq*ldb + n0 + blc;
    float4 fa = ldg4(Ap);
    float4 fb = ldg4(Bp);
    vf2 acc[2][4] = {};
    for (int kt = 0; kt < K; kt += 16) {
        __syncthreads();
        AsT[lq+0][lr]=fa.x; AsT[lq+1][lr]=fa.y; AsT[lq+2][lr]=fa.z; AsT[lq+3][lr]=fa.w;
        *reinterpret_cast<float4*>(&Bs[blq][blc]) = fb;
        __syncthreads();
        if (kt + 16 < K) {
            fa = ldg4(Ap + kt + 16);
            fb = ldg4(Bp + (size_t)(kt+16)*ldb);
        }
        #pragma unroll
        for (int q = 0; q < 16; q++) {
            float4 a = *reinterpret_cast<float4*>(&AsT[q][tm*4]);
            float4 b = *reinterpret_cast<float4*>(&Bs[q][tn*4]);
            vf2 a01 = {a.x, a.y}, a23 = {a.z, a.w};
            vf2 b0 = {b.x,b.x}, b1 = {b.y,b.y}, b2 = {b.z,b.z}, b3 = {b.w,b.w};
            acc[0][0] = fma2(a01, b0, acc[0][0]);
            acc[0][1] = fma2(a01, b1, acc[0][1]);
            acc[0][2] = fma2(a01, b2, acc[0][2]);
            acc[0][3] = fma2(a01, b3, acc[0][3]);
            acc[1][0] = fma2(a23, b0, acc[1][0]);
            acc[1][1] = fma2(a23, b1, acc[1][1]);
            acc[1][2] = fma2(a23, b2, acc[1][2]);
            acc[1][3] = fma2(a23, b3, acc[1][3]);
        }
    }
    #pragma unroll
    for (int h = 0; h < 2; h++) {
        int m = m0 + tm*4 + h*2;
        #pragma unroll
        for (int j = 0; j < 4; j++) {
            C[(size_t)m*ldc + n0 + tn*4 + j]     = acc[h][j].x;
            C[(size_t)(m+1)*ldc + n0 + tn*4 + j] = acc[h][j].y;
        }
    }
}

// one doubling level: fill H[mc..min(2mc,Lw)) = H[0..]*Apow^T ; square Apow
__global__ void __launch_bounds__(256) k_hlevel(float* __restrict__ Hbuf,
                                                float* __restrict__ apow,
                                                int par, int mc) {
    int s = blockIdx.z;
    int Lw = d_Lw(s);
    const float* Asrc = apow + (size_t)par*196608 + (size_t)s*65536;
    float* Adst       = apow + (size_t)(1-par)*196608 + (size_t)s*65536;
    float* H = Hbuf + d_Hoff(s);
    int yt = blockIdx.y, xt = blockIdx.x;
    if (yt < 4) {
        if (mc >= Lw) return;
        int rows = min(mc, Lw - mc);
        if (yt*64 >= rows) return;
        gemm64nt(H, 256, rows, Asrc, 256, H + (size_t)mc*256, 256,
                 yt*64, xt*64, 256);
    } else {
        if (2*mc >= Lw) return;
        gemm64nn(Asrc, 256, Asrc, 256, Adst, 256, (yt-4)*64, xt*64, 256);
    }
}

// ---------- blocked prefix scan for G ----------
__global__ void k_gscan1(const float* __restrict__ Hbuf, const float2* __restrict__ tw,
                         float2* __restrict__ psum) {
    int cg = blockIdx.x, k = blockIdx.y, n = threadIdx.x;
    int s, cl;
    if (cg < 2)      { s=0; cl=cg; }
    else if (cg < 6) { s=1; cl=cg-2; }
    else             { s=2; cl=cg-6; }
    int Lw = d_Lw(s);
    const float2* twk = tw + d_twoff(s) + (size_t)k*Lw;
    const float* H = Hbuf + d_Hoff(s);
    float pr = 0.f, pi = 0.f;
    int mbase = cl*CH;
    for (int mm = 0; mm < CH; mm++) {
        float h = H[(size_t)(mbase+mm)*256 + n];
        float2 t = twk[mbase+mm];
        pr = fmaf(t.x, h, pr);
        pi = fmaf(t.y, h, pi);
    }
    psum[((size_t)cg*32 + k)*256 + n] = make_float2(pr, pi);
}

__global__ void k_gscan2(const float* __restrict__ Hbuf, const float2* __restrict__ tw,
                         const float2* __restrict__ gt, const float2* __restrict__ psum,
                         float2* __restrict__ G2, int s, int cbase) {
    int cl = blockIdx.x, k = blockIdx.y, n = threadIdx.x;
    int Lw = d_Lw(s);
    const float2* twk = tw + d_twoff(s) + (size_t)k*Lw;
    const float2* gtk = gt + d_twoff(s) + (size_t)k*Lw;
    const float* H = Hbuf + d_Hoff(s);
    float pr = 0.f, pi = 0.f;
    for (int c = 0; c < cl; c++) {
        float2 p = psum[((size_t)(cbase+c)*32 + k)*256 + n];
        pr += p.x; pi += p.y;
    }
    int mbase = cl*CH;
    for (int mm = 0; mm < CH; mm++) {
        int m = mbase + mm;
        float h = H[(size_t)m*256 + n];
        float2 t = twk[m];
        pr = fmaf(t.x, h, pr);
        pi = fmaf(t.y, h, pi);
        int r = Lw-1-m;
        float2 g = gtk[r];
        G2[(size_t)r*8192 + k*256 + n] = make_float2(g.x*pr - g.y*pi, g.x*pi + g.y*pr);
    }
}

// pack B rows: Bp[(kk,n,0),o]=wr[n,o,k] ; Bp[(kk,n,1),o]=-wi[n,o,k]
__global__ void k_pack(const float* __restrict__ wr, const float* __restrict__ wi,
                       float* __restrict__ Bp, int s) {
    const float* WR = wr + (size_t)s*2097152;
    const float* WI = wi + (size_t)s*2097152;
    int n0 = blockIdx.x*4, o0 = blockIdx.y*32;
    __shared__ float sw[2][4][32][33];
    int tid = threadIdx.x;
    for (int idx = tid; idx < 8192; idx += 256) {
        int kk = idx & 31;
        int o  = (idx>>5) & 31;
        int n  = (idx>>10) & 3;
        int wsel = idx>>12;
        const float* W = wsel ? WI : WR;
        sw[wsel][n][o][kk] = W[(size_t)(n0+n)*8192 + (size_t)(o0+o)*32 + kk];
    }
    __syncthreads();
    for (int idx = tid; idx < 8192; idx += 256) {
        int o    = idx & 31;
        int part = (idx>>5) & 1;
        int n    = (idx>>6) & 3;
        int kk   = idx>>8;
        float v = part ? -sw[1][n][o][kk] : sw[0][n][o][kk];
        int R = kk*512 + (n0+n)*2 + part;
        Bp[(size_t)R*256 + o0 + o] = v;
    }
}

// big GEMM: parts[z] = G(BM-tile x Kblk) * Bp(Kblk x 64-tile); BM=64/128, 16 SK slices
template<int BM>
__global__ void __launch_bounds__(256) k_qgemmT(
    const float* __restrict__ G, const float* __restrict__ Bp,
    float* __restrict__ parts, int Lw, int Kblk)
{
    constexpr int TM = BM/16;     // per-thread rows (8 or 4)
    constexpr int F4 = TM/4;      // float4s per thread-row-frag (2 or 1)
    constexpr int TPR = 4/F4;     // A-stage threads per row
    const int Kd = 16384;
    int m0 = blockIdx.x*BM, n0 = blockIdx.y*64;
    int kb = blockIdx.z*Kblk;
    __shared__ __align__(16) float AsT[16][BM+4];
    __shared__ __align__(16) float Bs[16][68];
    int tid = threadIdx.x;
    int ty = tid >> 4, tx = tid & 15;
    int alr = tid / TPR;
    int akq = (tid % TPR) * 4 * F4;
    int bq = tid >> 4, bc = (tid & 15)*4;
    const float* Ap = G  + (size_t)(m0 + alr)*Kd + kb + akq;
    const float* Bq = Bp + (size_t)(kb + bq)*256 + n0 + bc;

    float4 fa[F4];
    #pragma unroll
    for (int f = 0; f < F4; f++) fa[f] = ldg4(Ap + 4*f);
    float4 fb = ldg4(Bq);

    vf2 acc[TM/2][4] = {};

    for (int kt = 0; kt < Kblk; kt += 16) {
        __syncthreads();
        #pragma unroll
        for (int f = 0; f < F4; f++) {
            AsT[akq+4*f+0][alr] = fa[f].x;
            AsT[akq+4*f+1][alr] = fa[f].y;
            AsT[akq+4*f+2][alr] = fa[f].z;
            AsT[akq+4*f+3][alr] = fa[f].w;
        }
        *reinterpret_cast<float4*>(&Bs[bq][bc]) = fb;
        __syncthreads();
        if (kt + 16 < Kblk) {
            #pragma unroll
            for (int f = 0; f < F4; f++) fa[f] = ldg4(Ap + kt + 16 + 4*f);
            fb = ldg4(Bq + (size_t)(kt+16)*256);
        }
        #pragma unroll
        for (int q = 0; q < 16; q++) {
            float4 b = *reinterpret_cast<float4*>(&Bs[q][tx*4]);
            vf2 bb[4] = {{b.x,b.x},{b.y,b.y},{b.z,b.z},{b.w,b.w}};
            #pragma unroll
            for (int f = 0; f < F4; f++) {
                float4 a = *reinterpret_cast<float4*>(&AsT[q][ty*TM + 4*f]);
                vf2 a01 = {a.x, a.y}, a23 = {a.z, a.w};
                #pragma unroll
                for (int j = 0; j < 4; j++) {
                    acc[f*2+0][j] = fma2(a01, bb[j], acc[f*2+0][j]);
                    acc[f*2+1][j] = fma2(a23, bb[j], acc[f*2+1][j]);
                }
            }
        }
    }
    #pragma unroll
    for (int i = 0; i < TM/2; i++) {
        int r0 = m0 + ty*TM + (i>>1)*4 + (i&1)*2;
        float* p = parts + ((size_t)blockIdx.z*Lw + r0)*256 + n0 + tx*4;
        float4 lo = make_float4(acc[i][0].x, acc[i][1].x, acc[i][2].x, acc[i][3].x);
        float4 hi = make_float4(acc[i][0].y, acc[i][1].y, acc[i][2].y, acc[i][3].y);
        *reinterpret_cast<float4*>(p)       = lo;
        *reinterpret_cast<float4*>(p + 256) = hi;
    }
}

__global__ void k_reduce(const float* __restrict__ parts, float* __restrict__ Q,
                         int Lw, int SK) {
    int i = blockIdx.x*256 + threadIdx.x;
    int tot = Lw*256;
    if (i >= tot) return;
    float v = 0.f;
    for (int z = 0; z < SK; z++) v += parts[(size_t)z*tot + i];
    Q[i] = v;
}

// T[r,p] = sum_o Q[r,o] * Esub[p,o]   (batched over all scales)
__global__ void __launch_bounds__(256) k_tgemm(const float* __restrict__ Qall,
                                               const float* __restrict__ E0,
                                               const float* __restrict__ E1,
                                               const float* __restrict__ E2,
                                               float* __restrict__ T) {
    int mtg = blockIdx.x;
    int s, lm, Lw, rowoff, Toff;
    if (mtg < 3)      { s=0; lm=mtg;   Lw=192; rowoff=0;   Toff=0; }
    else if (mtg < 9) { s=1; lm=mtg-3; Lw=384; rowoff=192; Toff=36864; }
    else              { s=2; lm=mtg-9; Lw=768; rowoff=576; Toff=110592; }
    const float* Es = (s==0) ? E0 : ((s==1) ? E1 : E2);
    gemm64nt(Qall + (size_t)rowoff*256, 256, Lw,
             Es + (size_t)(Lw-192)*256, 256,
             T + Toff, 192, lm*64, blockIdx.y*64, 256);
}

// Mtot[p,t] = sum_i mw[i] * T_i[t-off_i, p]
__global__ void k_mtot(const float* __restrict__ T, const float* __restrict__ mlpw,
                       float* __restrict__ M) {
    int i = blockIdx.x*256 + threadIdx.x;
    if (i >= 192*768) return;
    int p = i / 768, t = i % 768;
    float v = mlpw[2] * T[110592 + (size_t)t*192 + p];
    if (t >= 384) v += mlpw[1] * T[36864 + (size_t)(t-384)*192 + p];
    if (t >= 576) v += mlpw[0] * T[(size_t)(t-576)*192 + p];
    M[i] = v;
}

// out[b,p,j] = ((Mtot @ x)[p,(b,j)] + mb - ab[j])/(aw[j]+1e-10)*std + mean
__global__ void __launch_bounds__(256) k_final(
    const float* __restrict__ M, const float* __restrict__ xn,
    const float* __restrict__ aw, const float* __restrict__ ab,
    const float* __restrict__ meanb, const float* __restrict__ stdb,
    const float* __restrict__ mlpb, float* __restrict__ out)
{
    __shared__ float Ls[64][17];
    __shared__ float Bs[16][65];
    int p0 = blockIdx.x*64, c0 = blockIdx.y*64;
    int tid = threadIdx.x, tm = tid >> 4, tn = tid & 15;
    float acc[4][4] = {};
    for (int kt = 0; kt < 768; kt += 16) {
        __syncthreads();
        #pragma unroll
        for (int e = 0; e < 4; e++) {
            int idx = tid + e*256;
            int r = idx >> 4, q = idx & 15;
            Ls[r][q] = M[(size_t)(p0+r)*768 + kt + q];
        }
        #pragma unroll
        for (int e = 0; e < 4; e++) {
            int idx = tid + e*256;
            int q = idx >> 6, c = idx & 63;
            int cc = c0 + c;
            float v = 0.f;
            if (cc < BE) {
                int b = (cc >= ENC) ? 1 : 0;
                int j = cc - b*ENC;
                v = xn[(size_t)b*SEQ*ENC + (size_t)(kt+q)*ENC + j];
            }
            Bs[q][c] = v;
        }
        __syncthreads();
        #pragma unroll
        for (int q = 0; q < 16; q++) {
            float a[4], bb[4];
            #pragma unroll
            for (int i = 0; i < 4; i++) a[i]  = Ls[tm*4+i][q];
            #pragma unroll
            for (int j = 0; j < 4; j++) bb[j] = Bs[q][tn*4+j];
            #pragma unroll
            for (int i = 0; i < 4; i++)
                #pragma unroll
                for (int j = 0; j < 4; j++)
                    acc[i][j] = fmaf(a[i], bb[j], acc[i][j]);
        }
    }
    float mb = mlpb[0];
    #pragma unroll
    for (int i = 0; i < 4; i++) {
        int p = p0 + tm*4 + i;
        #pragma unroll
        for (int j = 0; j < 4; j++) {
            int cc = c0 + tn*4 + j;
            if (cc < BE) {
                int b = (cc >= ENC) ? 1 : 0;
                int jj = cc - b*ENC;
                float v = (acc[i][j] + mb - ab[jj]) / (aw[jj] + 1e-10f);
                v = v * stdb[b*ENC+jj] + meanb[b*ENC+jj];
                out[(size_t)b*(PRED*ENC) + (size_t)p*ENC + jj] = v;
            }
        }
    }
}

// ------------------------------------------------------------------
extern "C" void kernel_launch(void* const* d_in, const int* in_sizes, int n_in,
                              void* d_out, int out_size, void* d_ws, size_t ws_size,
                              hipStream_t stream)
{
    const float* hist = (const float*)d_in[0];
    const float* aw   = (const float*)d_in[2];
    const float* ab   = (const float*)d_in[3];
    const float* Ast  = (const float*)d_in[4];
    const float* Bst  = (const float*)d_in[5];
    const float* E0   = (const float*)d_in[6];
    const float* E1   = (const float*)d_in[7];
    const float* E2   = (const float*)d_in[8];
    const float* wr   = (const float*)d_in[9];
    const float* wi   = (const float*)d_in[10];
    const float* mlpw = (const float*)d_in[11];
    const float* mlpb = (const float*)d_in[12];
    float* out = (float*)d_out;

    float* w = (float*)d_ws;
    float* xn    = w; w += 493056;
    float* meanb = w; w += 642;
    float* stdb  = w; w += 642;
    float* Hbuf  = w; w += 344064;
    float* apow  = w; w += 2*3*65536;
    float2* tw   = (float2*)w; w += 86016;
    float2* gt   = (float2*)w; w += 86016;
    float2* psum = (float2*)w; w += 229376;
    float* Gst   = w; w += 12582912;          // 768 x 16384 (max scale)
    float* Bp    = w; w += 4194304;           // 16384 x 256 (per scale)
    float* parts = w; w += 3145728;           // 16 x 768 x 256 (max scale)
    float* Qall  = w; w += 344064;            // 1344 x 256
    float* Tbuf  = w; w += 258048;
    float* Mt    = w; w += 147456;
    // total 22,305,540 floats = 89.2 MB (proven available in R2)

    k_stats<<<dim3(6,2), dim3(64,4), 0, stream>>>(hist, meanb, stdb);
    k_norm<<<1926, 256, 0, stream>>>(hist, meanb, stdb, aw, ab, xn);
    k_tw<<<168, 256, 0, stream>>>(tw, gt);
    k_hinit<<<768, 256, 0, stream>>>(Ast, Bst, apow, Hbuf);
    for (int lev = 0; lev < 10; lev++)
        k_hlevel<<<dim3(4,8,3), 256, 0, stream>>>(Hbuf, apow, lev & 1, 1 << lev);

    k_gscan1<<<dim3(14,32), 256, 0, stream>>>(Hbuf, tw, psum);

    const int Lws[3]   = {192, 384, 768};
    const int cbase[3] = {0, 2, 6};
    const int rowoff[3]= {0, 192, 576};
    const int SK = 16, Kblk = 1024;
    for (int s = 0; s < 3; s++) {
        int Lw = Lws[s];
        k_gscan2<<<dim3(Lw/CH, 32), 256, 0, stream>>>(Hbuf, tw, gt, psum, (float2*)Gst, s, cbase[s]);
        k_pack<<<dim3(64,8), 256, 0, stream>>>(wr, wi, Bp, s);
        if (s == 0)
            k_qgemmT<64><<<dim3(3, 4, SK), 256, 0, stream>>>(Gst, Bp, parts, Lw, Kblk);
        else
            k_qgemmT<128><<<dim3(Lw/128, 4, SK), 256, 0, stream>>>(Gst, Bp, parts, Lw, Kblk);
        k_reduce<<<Lw, 256, 0, stream>>>(parts, Qall + (size_t)rowoff[s]*256, Lw, SK);
    }
    k_tgemm<<<dim3(21,3), 256, 0, stream>>>(Qall, E0, E1, E2, Tbuf);
    k_mtot<<<576, 256, 0, stream>>>(Tbuf, mlpw, Mt);
    k_final<<<dim3(3, 11), 256, 0, stream>>>(Mt, xn, aw, ab, meanb, stdb, mlpb, out);
}